// Round 1
// baseline (125.190 us; speedup 1.0000x reference)
//
#include <hip/hip_runtime.h>

typedef _Float16 half8  __attribute__((ext_vector_type(8)));
typedef _Float16 half4_t __attribute__((ext_vector_type(4)));
typedef float    f32x4  __attribute__((ext_vector_type(4)));

#define B_SZ    64
#define S_SZ    4096
#define H_SZ    256
#define CHUNKS  8
#define SCHUNK  512      // rows of S per block
#define TILE_R  64       // rows per A-tile
#define NTILES  (SCHUNK / TILE_R)   // 8
#define PAD_H   264      // 256 + 8 f16 pad -> row stride 528 B = 132 words = 4 banks shift

__device__ __forceinline__ float tanh_fast(float x) {
  // robust: x->+inf gives 1-0=1, x->-inf gives 1-2=-1, no NaN
  return 1.f - 2.f / (__expf(2.f * x) + 1.f);
}

// ---------------- kernel 0: bias[b][k] = sum_h final_h[b][h] * W2[k][h] ----------------
__global__ __launch_bounds__(256) void bias_kernel(const float* __restrict__ fh,
                                                   const float* __restrict__ W2,
                                                   float* __restrict__ bias) {
  const int b = blockIdx.x, k = threadIdx.x;
  __shared__ float fsh[H_SZ];
  fsh[k] = fh[b * H_SZ + k];
  __syncthreads();
  const float* wrow = W2 + (size_t)k * H_SZ;
  float s = 0.f;
#pragma unroll 4
  for (int h = 0; h < H_SZ; h += 4) {
    f32x4 w = *(const f32x4*)(wrow + h);
    s += w[0] * fsh[h] + w[1] * fsh[h + 1] + w[2] * fsh[h + 2] + w[3] * fsh[h + 3];
  }
  bias[b * H_SZ + k] = s;
}

// ---------------- kernel 1: fused proj -> tanh -> dot(v) -> online softmax -> context partials ----
// grid 512 = 64 b * 8 chunks; block 512 = 8 waves. Wave w owns output cols [32w, 32w+32).
__global__ __launch_bounds__(512, 2) void fused_kernel(const float* __restrict__ enc,
                                                       const float* __restrict__ W1,
                                                       const float* __restrict__ v,
                                                       const float* __restrict__ bias,
                                                       float* __restrict__ pc,   // [512][256]
                                                       float* __restrict__ pl,   // [512]
                                                       float* __restrict__ pm) { // [512]
  __shared__ _Float16 As[2][TILE_R][PAD_H] __attribute__((aligned(16)));  // 67.6 KB
  __shared__ float spart[8][TILE_R];   // per-wave col-slice score partials
  __shared__ float s_w[TILE_R];        // exp(s - m) weights for current tile
  __shared__ float cpart[8][H_SZ];     // per-wave context partials (epilogue)
  __shared__ float blk_m, blk_l, blk_rho;

  const int tid  = threadIdx.x;
  const int wave = tid >> 6;
  const int lane = tid & 63;
  const int nlo  = lane & 15;          // MFMA row/col-in-frag
  const int khi  = (lane >> 4) * 8;    // MFMA k-offset
  const int b     = blockIdx.x >> 3;
  const int chunk = blockIdx.x & 7;
  const size_t encBase = ((size_t)b * S_SZ + (size_t)chunk * SCHUNK) * H_SZ;

  // ---- W1 fragments in registers: B[k=h][n] = W1[n][h]; lane l: n = n0 + (l&15), k = ks*32 + khi + j
  half8 wf[2][8];
#pragma unroll
  for (int cf = 0; cf < 2; ++cf) {
    const int n = wave * 32 + cf * 16 + nlo;
    const float* wrow = W1 + (size_t)n * H_SZ + khi;
#pragma unroll
    for (int ks = 0; ks < 8; ++ks) {
      f32x4 w0 = *(const f32x4*)(wrow + ks * 32);
      f32x4 w1 = *(const f32x4*)(wrow + ks * 32 + 4);
      half8 h;
#pragma unroll
      for (int j = 0; j < 4; ++j) { h[j] = (_Float16)w0[j]; h[4 + j] = (_Float16)w1[j]; }
      wf[cf][ks] = h;
    }
  }
  const int n0c = wave * 32 + nlo;
  const float vv0 = v[n0c],      vv1 = v[n0c + 16];
  const float bv0 = bias[b * H_SZ + n0c], bv1 = bias[b * H_SZ + n0c + 16];

  if (tid == 0) { blk_m = -1e30f; blk_l = 0.f; }

  // context accumulators: lane covers h = 4*lane..4*lane+3 over this wave's rows
  float c0 = 0.f, c1 = 0.f, c2 = 0.f, c3 = 0.f;

  // prologue: issue loads for tile 0 (8 float4 per thread = 64 rows x 256 f32)
  f32x4 ld[8];
  {
    const float* src = enc + encBase;
#pragma unroll
    for (int i = 0; i < 8; ++i) ld[i] = *(const f32x4*)(src + (size_t)(tid + i * 512) * 4);
  }

#pragma unroll 1
  for (int t = 0; t < NTILES; ++t) {
    const int p = t & 1;
    // stage regs -> LDS (f32 -> f16, RNE)
#pragma unroll
    for (int i = 0; i < 8; ++i) {
      const int f4 = tid + i * 512;
      const int r = f4 >> 6, hq = (f4 & 63) * 4;
      half4_t hv;
      hv[0] = (_Float16)ld[i][0]; hv[1] = (_Float16)ld[i][1];
      hv[2] = (_Float16)ld[i][2]; hv[3] = (_Float16)ld[i][3];
      *(half4_t*)&As[p][r][hq] = hv;
    }
    // prefetch next tile into regs (in flight across the barrier + compute)
    if (t < NTILES - 1) {
      const float* src = enc + encBase + (size_t)(t + 1) * TILE_R * H_SZ;
#pragma unroll
      for (int i = 0; i < 8; ++i) ld[i] = *(const f32x4*)(src + (size_t)(tid + i * 512) * 4);
    }
    __syncthreads();   // As[p] visible

    // ---- MFMA: proj tile [64 x 32(this wave)] ; score partials
#pragma unroll
    for (int rf = 0; rf < 4; ++rf) {
      f32x4 d0 = {0.f, 0.f, 0.f, 0.f}, d1 = {0.f, 0.f, 0.f, 0.f};
#pragma unroll
      for (int ks = 0; ks < 8; ++ks) {
        half8 a = *(const half8*)&As[p][rf * 16 + nlo][ks * 32 + khi];
        d0 = __builtin_amdgcn_mfma_f32_16x16x32_f16(a, wf[0][ks], d0, 0, 0, 0);
        d1 = __builtin_amdgcn_mfma_f32_16x16x32_f16(a, wf[1][ks], d1, 0, 0, 0);
      }
      f32x4 s4;
#pragma unroll
      for (int i = 0; i < 4; ++i) {
        const float t0 = tanh_fast(d0[i] + bv0);
        const float t1 = tanh_fast(d1[i] + bv1);
        s4[i] = t0 * vv0 + t1 * vv1;
      }
      // reduce over the 16 cols held across lanes (l&15)
#pragma unroll
      for (int off = 1; off < 16; off <<= 1) {
        s4[0] += __shfl_xor(s4[0], off);
        s4[1] += __shfl_xor(s4[1], off);
        s4[2] += __shfl_xor(s4[2], off);
        s4[3] += __shfl_xor(s4[3], off);
      }
      if (nlo == 0)  // lanes 0,16,32,48 write rows rf*16 + (l>>4)*4 + i
        *(f32x4*)&spart[wave][rf * 16 + (lane >> 4) * 4] = s4;
    }
    __syncthreads();

    // ---- wave 0: combine col-slices, online-softmax bookkeeping
    if (wave == 0) {
      float s = 0.f;
#pragma unroll
      for (int w = 0; w < 8; ++w) s += spart[w][lane];
      float mt = s;
#pragma unroll
      for (int off = 1; off < 64; off <<= 1) mt = fmaxf(mt, __shfl_xor(mt, off));
      const float m_old = blk_m;
      const float m_new = fmaxf(m_old, mt);
      const float w_r = __expf(s - m_new);
      float ls = w_r;
#pragma unroll
      for (int off = 1; off < 64; off <<= 1) ls += __shfl_xor(ls, off);
      s_w[lane] = w_r;
      if (lane == 0) {
        const float rho = __expf(m_old - m_new);
        blk_rho = rho;
        blk_m = m_new;
        blk_l = blk_l * rho + ls;
      }
    }
    __syncthreads();

    // ---- context accumulation: wave w handles rows [8w, 8w+8), lane covers h=4*lane..+3
    const float rho = blk_rho;
    c0 *= rho; c1 *= rho; c2 *= rho; c3 *= rho;
#pragma unroll
    for (int rr = 0; rr < 8; ++rr) {
      const int r = wave * 8 + rr;
      const float wr = s_w[r];
      half4_t a = *(const half4_t*)&As[p][r][lane * 4];
      c0 += wr * (float)a[0];
      c1 += wr * (float)a[1];
      c2 += wr * (float)a[2];
      c3 += wr * (float)a[3];
    }
    // no barrier needed: next iteration writes As[1-p]; spart/s_w rewrites are behind 2 barriers
  }

  // ---- epilogue: combine per-wave context partials
  {
    f32x4 cv; cv[0] = c0; cv[1] = c1; cv[2] = c2; cv[3] = c3;
    *(f32x4*)&cpart[wave][lane * 4] = cv;
  }
  __syncthreads();
  if (tid < H_SZ) {
    float s = 0.f;
#pragma unroll
    for (int w = 0; w < 8; ++w) s += cpart[w][tid];
    pc[(size_t)blockIdx.x * H_SZ + tid] = s;
  }
  if (tid == 0) { pl[blockIdx.x] = blk_l; pm[blockIdx.x] = blk_m; }
}

// ---------------- kernel 2: merge 8 chunk partials per batch ----------------
__global__ __launch_bounds__(256) void combine_kernel(const float* __restrict__ pc,
                                                      const float* __restrict__ pl,
                                                      const float* __restrict__ pm,
                                                      float* __restrict__ out) {
  const int b = blockIdx.x, h = threadIdx.x;
  float M = -1e30f;
#pragma unroll
  for (int j = 0; j < CHUNKS; ++j) M = fmaxf(M, pm[b * CHUNKS + j]);
  float L = 0.f, s = 0.f;
#pragma unroll
  for (int j = 0; j < CHUNKS; ++j) {
    const float e = __expf(pm[b * CHUNKS + j] - M);
    L += pl[b * CHUNKS + j] * e;
    s += e * pc[(size_t)(b * CHUNKS + j) * H_SZ + h];
  }
  out[b * H_SZ + h] = s / L;
}

extern "C" void kernel_launch(void* const* d_in, const int* in_sizes, int n_in,
                              void* d_out, int out_size, void* d_ws, size_t ws_size,
                              hipStream_t stream) {
  const float* enc = (const float*)d_in[0];  // [64,4096,256]
  const float* fh  = (const float*)d_in[1];  // [64,256]
  const float* W1  = (const float*)d_in[2];  // [256,256]
  const float* W2  = (const float*)d_in[3];  // [256,256]
  const float* v   = (const float*)d_in[4];  // [256]
  float* out = (float*)d_out;                // [64,256]

  float* ws   = (float*)d_ws;
  float* bias = ws;                          // 64*256
  float* pc   = ws + B_SZ * H_SZ;            // 512*256
  float* pl   = pc + B_SZ * CHUNKS * H_SZ;   // 512
  float* pm   = pl + B_SZ * CHUNKS;          // 512

  bias_kernel<<<B_SZ, H_SZ, 0, stream>>>(fh, W2, bias);
  fused_kernel<<<B_SZ * CHUNKS, 512, 0, stream>>>(enc, W1, v, bias, pc, pl, pm);
  combine_kernel<<<B_SZ, H_SZ, 0, stream>>>(pc, pl, pm, out);
}